// Round 2
// baseline (644.640 us; speedup 1.0000x reference)
//
#include <hip/hip_runtime.h>

#define NB 8
#define NH 56
#define NW 56
#define NHW 3136          // NH*NW
#define NCHW 802816
#define NPIX 25088        // NB*NHW
#define NHP 58            // padded dim
#define EPSV 1e-5f

typedef float f32x4 __attribute__((ext_vector_type(4)));
typedef __bf16 bf16x8 __attribute__((ext_vector_type(8)));

__device__ __forceinline__ unsigned short f2b(float f) {   // RNE (epilogues)
  unsigned int u = __float_as_uint(f);
  u += 0x7FFFu + ((u >> 16) & 1u);
  return (unsigned short)(u >> 16);
}
__device__ __forceinline__ float blo(unsigned int u){ return __uint_as_float(u << 16); }
__device__ __forceinline__ float bhi(unsigned int u){ return __uint_as_float(u & 0xFFFF0000u); }
// pack 2 fp32 -> 2 bf16 (truncation) in ONE v_perm
__device__ __forceinline__ unsigned int pack_trunc(float f0, float f1) {
  return __builtin_amdgcn_perm(__float_as_uint(f1), __float_as_uint(f0), 0x07060302u);
}
// barrier WITHOUT vmcnt drain: ds_writes visible (lgkmcnt 0), prefetch loads stay in flight
__device__ __forceinline__ void soft_barrier() {
  __builtin_amdgcn_s_waitcnt(0xC07F);   // vmcnt=63, expcnt=7, lgkmcnt=0
  __builtin_amdgcn_s_barrier();
}

// ---------------------------------------------------------------------------
// P0: zero the 1px borders of xbp and t1b (replaces 27.5MB memset)
// ---------------------------------------------------------------------------
__global__ __launch_bounds__(256) void clear_borders(
    unsigned short* __restrict__ xbp, unsigned short* __restrict__ t1b)
{
  int i = blockIdx.x*256 + threadIdx.x;        // 58368 exact
  int q = i & 31; int pid = i >> 5;
  int b = pid / 228, j = pid % 228;
  int y, x;
  if (j < 58)       { y = 0;  x = j; }
  else if (j < 116) { y = 57; x = j - 58; }
  else { int jj = j - 116; y = 1 + (jj >> 1); x = (jj & 1) * 57; }
  size_t addr = ((size_t)(b*NHP + y)*NHP + x)*256 + q*8;
  uint4 z = make_uint4(0u,0u,0u,0u);
  *(uint4*)(xbp + addr) = z;
  *(uint4*)(t1b + addr) = z;
}

// ---------------------------------------------------------------------------
// P1: x NCHW fp32 -> xbp padded NHWC bf16 (interior only)
// ---------------------------------------------------------------------------
__global__ __launch_bounds__(256) void prep_x(
    const float* __restrict__ x, unsigned short* __restrict__ xbp)
{
  __shared__ float T[64][65];
  const int pxt  = blockIdx.x * 64;       // never crosses b (3136 = 49*64)
  const int cg   = blockIdx.y * 64;
  const int b    = pxt / NHW;
  const int rem0 = pxt % NHW;
  const int t    = threadIdx.x;
  const int pl   = t & 63;
  const int c0   = t >> 6;
  const float* src = x + (size_t)b*NCHW + rem0;
  #pragma unroll
  for (int it = 0; it < 16; ++it) {
    int c = c0 + it*4;
    T[c][pl] = src[(size_t)(cg + c)*NHW + pl];
  }
  __syncthreads();
  const int pr = t >> 5;
  const int cp = t & 31;
  #pragma unroll
  for (int it = 0; it < 8; ++it) {
    int pxl = pr + it*8;
    int rem = rem0 + pxl;
    int ho = rem / NW, wo = rem % NW;
    unsigned int pk = ((unsigned int)f2b(T[cp*2+1][pxl]) << 16) | (unsigned int)f2b(T[cp*2][pxl]);
    *(unsigned int*)(xbp + ((size_t)(b*NHP + ho + 1)*NHP + (wo + 1))*256 + cg + cp*2) = pk;
  }
}

// ---------------------------------------------------------------------------
// P2: w [co][ci][3][3] fp32 -> wp [co][k*256+ci] bf16
// ---------------------------------------------------------------------------
__global__ __launch_bounds__(256) void prep_w(
    const float* __restrict__ w, unsigned short* __restrict__ wp)
{
  int i = blockIdx.x*256 + threadIdx.x;    // 589824 exact
  int co = i / 2304;
  int r  = i % 2304;
  int k  = r >> 8;
  int ci = r & 255;
  wp[i] = f2b(w[((size_t)co*256 + ci)*9 + k]);
}

// P3: off_w [18][256][3][3] -> w3p [32 rows][k*256+ci] bf16, rows 18..31 = 0
__global__ __launch_bounds__(256) void prep_w3(
    const float* __restrict__ ow, unsigned short* __restrict__ w3p)
{
  int i = blockIdx.x*256 + threadIdx.x;    // 73728 exact
  int co = i / 2304;
  int r  = i % 2304;
  int k  = r >> 8;
  int ci = r & 255;
  w3p[i] = (co < 18) ? f2b(ow[((size_t)co*256 + ci)*9 + k]) : (unsigned short)0;
}

// ---------------------------------------------------------------------------
// GEMM1: conv3x3 + BN + ReLU -> t1b padded NHWC bf16
// N-split: BM=64 BN=128 BK=64, 256 thr = 4 waves (2M x 2N), wave tile 32x64
// grid (392,2) = 784 blocks; XCD swizzle: 49 blocks/XCD per by = one batch/XCD
// ---------------------------------------------------------------------------
__global__ __launch_bounds__(256, 4) void gemm_conv1(
    const unsigned short* __restrict__ xbp, const unsigned short* __restrict__ w1p,
    const float* __restrict__ gam, const float* __restrict__ bet,
    const float* __restrict__ mu,  const float* __restrict__ var,
    unsigned short* __restrict__ t1b)
{
  __shared__ unsigned short SMEM[12288];     // Al 4096 | Bl 8192 (24KB)
  unsigned short* Al = SMEM;
  unsigned short* Bl = SMEM + 4096;

  const int bx   = blockIdx.x;
  const int nbx  = (bx & 7)*49 + (bx >> 3);   // 392 = 8*49, batch-per-XCD
  const int m0   = nbx * 64;
  const int n0   = blockIdx.y * 128;

  const int t    = threadIdx.x;
  const int lane = t & 63;
  const int wv   = t >> 6;       // 0..3
  const int wvM  = wv & 1;
  const int wvN  = wv >> 1;      // 0..1
  const int quad = lane >> 4;
  const int l15  = lane & 15;

  const int srow = t >> 3;       // 0..31
  const int seg  = t & 7;
  const int sxor = srow & 7;     // (srow+32)&7 == srow&7

  // two A rows per thread: srow and srow+32
  unsigned int pbA0, pbA1;
  {
    int px0 = m0 + srow;
    int b0 = px0 / NHW, rem0 = px0 % NHW;
    pbA0 = ((unsigned int)(b0*NHP + rem0/NW)*NHP + rem0%NW)*256u + seg*8u;
    int px1 = px0 + 32;
    int b1 = px1 / NHW, rem1 = px1 % NHW;
    pbA1 = ((unsigned int)(b1*NHP + rem1/NW)*NHP + rem1%NW)*256u + seg*8u;
  }

  f32x4 acc[2][4];
  #pragma unroll
  for (int i = 0; i < 2; ++i)
    #pragma unroll
    for (int j = 0; j < 4; ++j) acc[i][j] = (f32x4)(0.f);

  uint4 pA0, pA1, pB[4];
  {   // prefetch r=0 (k=0 -> ky=kx=0, cic=0)
    pA0 = *(const uint4*)(xbp + pbA0);
    pA1 = *(const uint4*)(xbp + pbA1);
    #pragma unroll
    for (int i = 0; i < 4; ++i)
      pB[i] = *(const uint4*)(w1p + (size_t)(n0 + srow + 32*i)*2304 + seg*8u);
  }

  for (int r = 0; r < 36; ++r) {
    __syncthreads();                                      // barrier1 (drains prefetch)
    *(uint4*)(&Al[(srow     )*64 + ((seg ^ sxor)*8)]) = pA0;
    *(uint4*)(&Al[(srow + 32)*64 + ((seg ^ sxor)*8)]) = pA1;
    #pragma unroll
    for (int i = 0; i < 4; ++i)
      *(uint4*)(&Bl[(srow + 32*i)*64 + ((seg ^ sxor)*8)]) = pB[i];
    {   // prefetch r+1 (clamped; redundant reload on last iter)
      const int rn = (r < 35) ? r + 1 : 35;
      const int kn = rn >> 2, cicn = rn & 3;
      const int kyn = kn/3, kxn = kn - kyn*3;
      const unsigned int koff = (unsigned int)((kyn*NHP + kxn)*256 + cicn*64);
      pA0 = *(const uint4*)(xbp + pbA0 + koff);
      pA1 = *(const uint4*)(xbp + pbA1 + koff);
      const unsigned int rb = (unsigned int)(rn*64) + seg*8u;
      #pragma unroll
      for (int i = 0; i < 4; ++i)
        pB[i] = *(const uint4*)(w1p + (size_t)(n0 + srow + 32*i)*2304 + rb);
    }
    soft_barrier();                                       // barrier2: no vmcnt drain
    #pragma unroll
    for (int kk = 0; kk < 2; ++kk) {
      const int s8 = (kk*4 + quad) ^ (l15 & 7);
      bf16x8 af[2], bfr[4];
      #pragma unroll
      for (int mt = 0; mt < 2; ++mt)
        af[mt] = *(const bf16x8*)(&Al[(wvM*32 + mt*16 + l15)*64 + s8*8]);
      #pragma unroll
      for (int nt = 0; nt < 4; ++nt)
        bfr[nt] = *(const bf16x8*)(&Bl[(wvN*64 + nt*16 + l15)*64 + s8*8]);
      #pragma unroll
      for (int mt = 0; mt < 2; ++mt)
        #pragma unroll
        for (int nt = 0; nt < 4; ++nt)
          acc[mt][nt] = __builtin_amdgcn_mfma_f32_16x16x32_bf16(af[mt], bfr[nt], acc[mt][nt], 0, 0, 0);
    }
  }

  // epilogue: BN+ReLU -> per-wave bounce (32px x 72 shorts) -> padded t1b
  __syncthreads();
  unsigned short* Sw = SMEM + wv*2304;     // 4*2304 = 9216 <= 12288
  #pragma unroll
  for (int nt = 0; nt < 4; ++nt) {
    const int co = n0 + wvN*64 + nt*16 + l15;
    const float inv  = gam[co] * rsqrtf(var[co] + EPSV);
    const float beta = bet[co] - mu[co]*inv;
    #pragma unroll
    for (int mt = 0; mt < 2; ++mt) {
      #pragma unroll
      for (int rr = 0; rr < 4; ++rr) {
        const int pxl = mt*16 + quad*4 + rr;
        float val = acc[mt][nt][rr]*inv + beta;
        val = val > 0.f ? val : 0.f;
        Sw[pxl*72 + nt*16 + l15] = f2b(val);
      }
    }
  }
  #pragma unroll
  for (int i = 0; i < 4; ++i) {
    const int pxl = (lane >> 3) + 8*i;
    const int sc  = lane & 7;
    uint4 q = *(const uint4*)(&Sw[pxl*72 + sc*8]);
    const int pg = m0 + wvM*32 + pxl;
    const int bb = pg / NHW, rm = pg % NHW;
    const int hh = rm / NW, ww = rm % NW;
    *(uint4*)(t1b + ((size_t)(bb*NHP + hh + 1)*NHP + ww + 1)*256 + n0 + wvN*64 + sc*8) = q;
  }
}

// ---------------------------------------------------------------------------
// GEMM-OFF: offset conv, split-K x4 (9 rounds each), atomicAdd into toff
// + XCD swizzle on bx (392%8==0 so linear id %8 == bx%8 for all by)
// ---------------------------------------------------------------------------
__global__ __launch_bounds__(256, 8) void gemm_off(
    const unsigned short* __restrict__ t1b, const unsigned short* __restrict__ w3p,
    const float* __restrict__ ob, float* __restrict__ toff)
{
  __shared__ unsigned short Al[4096];   // 64x64
  __shared__ unsigned short Bl[2048];   // 32x64

  const int bx  = blockIdx.x;
  const int nbx = (bx & 7)*49 + (bx >> 3);
  const int m0  = nbx * 64;
  const int kc = blockIdx.y;            // K chunk 0..3
  const int t    = threadIdx.x;
  const int lane = t & 63;
  const int wv   = t >> 6;
  const int quad = lane >> 4;
  const int l15  = lane & 15;

  const int arow = t >> 2;      // 0..63
  const int as4  = t & 3;
  const int axor = arow & 7;
  const int pxa  = m0 + arow;
  const int ba   = pxa / NHW, rema = pxa % NHW;
  const unsigned int pbase = ((unsigned int)(ba*NHP + rema/NW)*NHP + rema%NW)*256u;

  const int brow = t >> 3;      // 0..31
  const int bs   = t & 7;

  f32x4 acc[2];
  #pragma unroll
  for (int nt = 0; nt < 2; ++nt) {
    float init = 0.f;
    if (kc == 0) { int co = nt*16 + l15; init = (co < 18) ? ob[co] : 0.f; }
    acc[nt] = (f32x4)(init);
  }

  uint4 pA0, pA1, pB;
  {   // prefetch first round r = kc*9
    const int r = kc*9, k = r >> 2, cic = r & 3;
    const int ky = k/3, kx = k - ky*3;
    const unsigned int base = pbase + (unsigned int)((ky*NHP + kx)*256 + cic*64);
    pA0 = *(const uint4*)(t1b + base + as4*8);
    pA1 = *(const uint4*)(t1b + base + (as4+4)*8);
    pB  = *(const uint4*)(w3p + (size_t)brow*2304 + r*64 + bs*8);
  }

  for (int rr = 0; rr < 9; ++rr) {
    const int r = kc*9 + rr;
    __syncthreads();
    *(uint4*)(&Al[arow*64 + ((as4     ^ axor)*8)]) = pA0;
    *(uint4*)(&Al[arow*64 + (((as4+4) ^ axor)*8)]) = pA1;
    *(uint4*)(&Bl[brow*64 + ((bs ^ (brow & 7))*8)]) = pB;
    {
      const int rn = (rr < 8) ? r + 1 : r;
      const int kn = rn >> 2, cicn = rn & 3;
      const int kyn = kn/3, kxn = kn - kyn*3;
      const unsigned int base = pbase + (unsigned int)((kyn*NHP + kxn)*256 + cicn*64);
      pA0 = *(const uint4*)(t1b + base + as4*8);
      pA1 = *(const uint4*)(t1b + base + (as4+4)*8);
      pB  = *(const uint4*)(w3p + (size_t)brow*2304 + rn*64 + bs*8);
    }
    soft_barrier();
    #pragma unroll
    for (int kk = 0; kk < 2; ++kk) {
      const int s8 = (kk*4 + quad) ^ (l15 & 7);
      bf16x8 af = *(const bf16x8*)(&Al[(wv*16 + l15)*64 + s8*8]);
      #pragma unroll
      for (int nt = 0; nt < 2; ++nt) {
        bf16x8 bfr = *(const bf16x8*)(&Bl[(nt*16 + l15)*64 + s8*8]);
        acc[nt] = __builtin_amdgcn_mfma_f32_16x16x32_bf16(af, bfr, acc[nt], 0, 0, 0);
      }
    }
  }
  #pragma unroll
  for (int nt = 0; nt < 2; ++nt) {
    const int co = nt*16 + l15;
    if (co < 18) {
      #pragma unroll
      for (int rr2 = 0; rr2 < 4; ++rr2) {
        const int pg = m0 + wv*16 + quad*4 + rr2;
        const int bb = pg / NHW, rm = pg % NHW;
        atomicAdd(&toff[(size_t)bb*(18*NHW) + (size_t)co*NHW + rm], acc[nt][rr2]);
      }
    }
  }
}

// ---------------------------------------------------------------------------
// GEMM2: deform_conv + BN + residual + ReLU -> out NCHW fp32
// M-split: BM=32 BN=256 BK=64, 256 thr = 4 waves (1M x 4N), wave tile 32x64
// grid 784; XCD swizzle: 98 blocks/XCD = exactly one batch per XCD L2
// ---------------------------------------------------------------------------
__global__ __launch_bounds__(256, 3) void gemm_deform(
    const unsigned short* __restrict__ t1b, const unsigned short* __restrict__ w2p,
    const float* __restrict__ toff, const float* __restrict__ xres,
    const float* __restrict__ gam, const float* __restrict__ bet,
    const float* __restrict__ mu,  const float* __restrict__ var,
    float* __restrict__ outp)
{
  __shared__ unsigned short SMEM[18432];     // Al 2048 | Bl 16384 (36KB)
  unsigned short* Al = SMEM;
  unsigned short* Bl = SMEM + 2048;

  const int bid  = blockIdx.x;
  const int nb   = (bid & 7)*98 + (bid >> 3);   // 784 = 8*98, batch-per-XCD
  const int m0   = nb * 32;
  const int t    = threadIdx.x;
  const int lane = t & 63;
  const int wv   = t >> 6;       // 0..3 (N groups of 64)
  const int quad = lane >> 4;
  const int l15  = lane & 15;

  const int srow = t >> 3;     // 0..31
  const int seg  = t & 7;
  const int sxor = srow & 7;   // (srow+32*i)&7 == srow&7
  const int px   = m0 + srow;
  const int b    = px / NHW, rem = px % NHW;
  const int ho   = rem / NW, wo = rem % NW;
  const int obb  = b*(18*NHW) + rem;
  const unsigned int prowb = (unsigned int)(b*NHP);

  f32x4 acc[2][4];
  #pragma unroll
  for (int i = 0; i < 2; ++i)
    #pragma unroll
    for (int j = 0; j < 4; ++j) acc[i][j] = (f32x4)(0.f);

  // bilinear coord state for current k
  unsigned int o00, o01, o10, o11;
  float w00, w01, w10, w11;
#define COORDS(KK) {                                                   \
    const int ky_ = (KK)/3, kx_ = (KK) - ky_*3;                        \
    const float offy = toff[obb + (KK)*NHW];                           \
    const float offx = toff[obb + (9+(KK))*NHW];                       \
    const float yf = (float)(ho - 1 + ky_) + offy;                     \
    const float xf = (float)(wo - 1 + kx_) + offx;                     \
    const float y0f = floorf(yf), x0f = floorf(xf);                    \
    const float ty = yf - y0f,   tx = xf - x0f;                        \
    const int y0p = (int)y0f + 1, x0p = (int)x0f + 1;                  \
    const int cy0 = min(max(y0p,   0), NHP-1);                         \
    const int cy1 = min(max(y0p+1, 0), NHP-1);                         \
    const int cx0 = min(max(x0p,   0), NHP-1);                         \
    const int cx1 = min(max(x0p+1, 0), NHP-1);                         \
    w00 = (1.f-ty)*(1.f-tx);  w01 = (1.f-ty)*tx;                       \
    w10 = ty*(1.f-tx);        w11 = ty*tx;                             \
    o00 = ((prowb + cy0)*NHP + cx0)*256u + seg*8u;                     \
    o01 = ((prowb + cy0)*NHP + cx1)*256u + seg*8u;                     \
    o10 = ((prowb + cy1)*NHP + cx0)*256u + seg*8u;                     \
    o11 = ((prowb + cy1)*NHP + cx1)*256u + seg*8u;                     \
  }

  COORDS(0);
  uint4 pc00, pc01, pc10, pc11, pB[8];
  {   // prefetch r=0 (cic=0)
    pc00 = *(const uint4*)(t1b + o00);
    pc01 = *(const uint4*)(t1b + o01);
    pc10 = *(const uint4*)(t1b + o10);
    pc11 = *(const uint4*)(t1b + o11);
    #pragma unroll
    for (int i = 0; i < 8; ++i)
      pB[i] = *(const uint4*)(w2p + (size_t)(srow + 32*i)*2304 + seg*8u);
  }

  for (int r = 0; r < 36; ++r) {
    __syncthreads();                                   // barrier1
    {   // bilinear + pack from prefetched corners -> Al
      uint4 res;
      {
        float a0 = w00*blo(pc00.x) + w01*blo(pc01.x) + w10*blo(pc10.x) + w11*blo(pc11.x);
        float a1 = w00*bhi(pc00.x) + w01*bhi(pc01.x) + w10*bhi(pc10.x) + w11*bhi(pc11.x);
        res.x = pack_trunc(a0, a1);
      }
      {
        float a0 = w00*blo(pc00.y) + w01*blo(pc01.y) + w10*blo(pc10.y) + w11*blo(pc11.y);
        float a1 = w00*bhi(pc00.y) + w01*bhi(pc01.y) + w10*bhi(pc10.y) + w11*bhi(pc11.y);
        res.y = pack_trunc(a0, a1);
      }
      {
        float a0 = w00*blo(pc00.z) + w01*blo(pc01.z) + w10*blo(pc10.z) + w11*blo(pc11.z);
        float a1 = w00*bhi(pc00.z) + w01*bhi(pc01.z) + w10*bhi(pc10.z) + w11*bhi(pc11.z);
        res.z = pack_trunc(a0, a1);
      }
      {
        float a0 = w00*blo(pc00.w) + w01*blo(pc01.w) + w10*blo(pc10.w) + w11*blo(pc11.w);
        float a1 = w00*bhi(pc00.w) + w01*bhi(pc01.w) + w10*bhi(pc10.w) + w11*bhi(pc11.w);
        res.w = pack_trunc(a0, a1);
      }
      *(uint4*)(&Al[srow*64 + ((seg ^ sxor)*8)]) = res;
    }
    #pragma unroll
    for (int i = 0; i < 8; ++i)
      *(uint4*)(&Bl[(srow + 32*i)*64 + ((seg ^ sxor)*8)]) = pB[i];
    {   // coords for next k, then prefetch r+1
      if ((r & 3) == 3 && r < 35) COORDS((r+1) >> 2);
      const int rn = (r < 35) ? r + 1 : 35;
      const unsigned int cio = (unsigned int)((rn & 3)*64);
      pc00 = *(const uint4*)(t1b + o00 + cio);
      pc01 = *(const uint4*)(t1b + o01 + cio);
      pc10 = *(const uint4*)(t1b + o10 + cio);
      pc11 = *(const uint4*)(t1b + o11 + cio);
      const unsigned int rb = (unsigned int)(rn*64) + seg*8u;
      #pragma unroll
      for (int i = 0; i < 8; ++i)
        pB[i] = *(const uint4*)(w2p + (size_t)(srow + 32*i)*2304 + rb);
    }
    soft_barrier();                                    // barrier2: no vmcnt drain
    #pragma unroll
    for (int kk = 0; kk < 2; ++kk) {
      const int s8 = (kk*4 + quad) ^ (l15 & 7);
      bf16x8 af[2], bfr[4];
      #pragma unroll
      for (int mt = 0; mt < 2; ++mt)
        af[mt] = *(const bf16x8*)(&Al[(mt*16 + l15)*64 + s8*8]);
      #pragma unroll
      for (int nt = 0; nt < 4; ++nt)
        bfr[nt] = *(const bf16x8*)(&Bl[(wv*64 + nt*16 + l15)*64 + s8*8]);
      #pragma unroll
      for (int mt = 0; mt < 2; ++mt)
        #pragma unroll
        for (int nt = 0; nt < 4; ++nt)
          acc[mt][nt] = __builtin_amdgcn_mfma_f32_16x16x32_bf16(af[mt], bfr[nt], acc[mt][nt], 0, 0, 0);
    }
  }
#undef COORDS

  // epilogue: per-wave f32 bounce (32px x 33), 2 co-halves -> coalesced NCHW
  __syncthreads();
  float* Sl = (float*)SMEM + wv*1056;     // 4*4224B = 16.9KB <= 36KB
  const int pxl_r = lane & 31;
  const int csel  = lane >> 5;
  const int pg    = m0 + pxl_r;
  const int bo    = pg / NHW, remo = pg % NHW;
  const size_t obase = (size_t)bo*NCHW + remo;
  #pragma unroll
  for (int h = 0; h < 2; ++h) {
    #pragma unroll
    for (int nt2 = 0; nt2 < 2; ++nt2) {
      const int nt = h*2 + nt2;
      #pragma unroll
      for (int mt = 0; mt < 2; ++mt) {
        #pragma unroll
        for (int rr = 0; rr < 4; ++rr) {
          const int pxl = mt*16 + quad*4 + rr;
          Sl[pxl*33 + nt2*16 + l15] = acc[mt][nt][rr];
        }
      }
    }
    #pragma unroll
    for (int j = 0; j < 16; ++j) {
      const int col = csel*16 + j;
      const int co  = wv*64 + h*32 + col;
      const float inv  = gam[co] * rsqrtf(var[co] + EPSV);
      const float beta = bet[co] - mu[co]*inv;
      const size_t off = obase + (size_t)co*NHW;
      float val = Sl[pxl_r*33 + col];
      float o = val*inv + beta + xres[off];
      outp[off] = o > 0.f ? o : 0.f;
    }
  }
}

extern "C" void kernel_launch(void* const* d_in, const int* in_sizes, int n_in,
                              void* d_out, int out_size, void* d_ws, size_t ws_size,
                              hipStream_t stream) {
  const float* x   = (const float*)d_in[0];
  const float* w1  = (const float*)d_in[1];
  const float* g1  = (const float*)d_in[2];
  const float* b1  = (const float*)d_in[3];
  const float* m1  = (const float*)d_in[4];
  const float* v1  = (const float*)d_in[5];
  const float* ow  = (const float*)d_in[6];
  const float* ob  = (const float*)d_in[7];
  const float* w2  = (const float*)d_in[8];
  const float* g2  = (const float*)d_in[9];
  const float* b2  = (const float*)d_in[10];
  const float* m2  = (const float*)d_in[11];
  const float* v2  = (const float*)d_in[12];
  float* out = (float*)d_out;

  const size_t PADSZ = (size_t)NB*NHP*NHP*256;
  unsigned short* xbp = (unsigned short*)d_ws;
  unsigned short* t1b = xbp + PADSZ;
  float*          tof = (float*)(t1b + PADSZ);
  unsigned short* w1p = (unsigned short*)(tof + (size_t)NB*18*NHW);
  unsigned short* w2p = w1p + (size_t)589824;
  unsigned short* w3p = w2p + (size_t)589824;

  clear_borders<<<228, 256, 0, stream>>>(xbp, t1b);
  dim3 gp(392, 4, 1);
  prep_x<<<gp, 256, 0, stream>>>(x, xbp);
  prep_w<<<2304, 256, 0, stream>>>(w1, w1p);
  prep_w<<<2304, 256, 0, stream>>>(w2, w2p);
  prep_w3<<<288, 256, 0, stream>>>(ow, w3p);
  hipMemsetAsync(tof, 0, (size_t)NB*18*NHW*sizeof(float), stream);

  dim3 g1d(392, 2, 1);
  gemm_conv1<<<g1d, 256, 0, stream>>>(xbp, w1p, g1, b1, m1, v1, t1b);
  dim3 go(392, 4, 1);
  gemm_off<<<go, 256, 0, stream>>>(t1b, w3p, ob, tof);
  gemm_deform<<<784, 256, 0, stream>>>(t1b, w2p, tof, x, g2, b2, m2, v2, out);
}

// Round 3
// 278.371 us; speedup vs baseline: 2.3158x; 2.3158x over previous
//
#include <hip/hip_runtime.h>

#define NB 8
#define NH 56
#define NW 56
#define NHW 3136          // NH*NW
#define NCHW 802816
#define NPIX 25088        // NB*NHW
#define NHP 58            // padded dim
#define EPSV 1e-5f

typedef float f32x4 __attribute__((ext_vector_type(4)));
typedef __bf16 bf16x8 __attribute__((ext_vector_type(8)));

__device__ __forceinline__ unsigned short f2b(float f) {   // RNE (epilogues)
  unsigned int u = __float_as_uint(f);
  u += 0x7FFFu + ((u >> 16) & 1u);
  return (unsigned short)(u >> 16);
}
__device__ __forceinline__ float blo(unsigned int u){ return __uint_as_float(u << 16); }
__device__ __forceinline__ float bhi(unsigned int u){ return __uint_as_float(u & 0xFFFF0000u); }
// pack 2 fp32 -> 2 bf16 (truncation) in ONE v_perm
__device__ __forceinline__ unsigned int pack_trunc(float f0, float f1) {
  return __builtin_amdgcn_perm(__float_as_uint(f1), __float_as_uint(f0), 0x07060302u);
}
// barrier WITHOUT vmcnt drain: ds_writes visible (lgkmcnt 0), prefetch loads stay in flight
__device__ __forceinline__ void soft_barrier() {
  __builtin_amdgcn_s_waitcnt(0xC07F);   // vmcnt=63, expcnt=7, lgkmcnt=0
  __builtin_amdgcn_s_barrier();
}

// ---------------------------------------------------------------------------
// P0: zero the 1px borders of xbp and t1b (replaces 27.5MB memset)
// ---------------------------------------------------------------------------
__global__ __launch_bounds__(256) void clear_borders(
    unsigned short* __restrict__ xbp, unsigned short* __restrict__ t1b)
{
  int i = blockIdx.x*256 + threadIdx.x;        // 58368 exact
  int q = i & 31; int pid = i >> 5;
  int b = pid / 228, j = pid % 228;
  int y, x;
  if (j < 58)       { y = 0;  x = j; }
  else if (j < 116) { y = 57; x = j - 58; }
  else { int jj = j - 116; y = 1 + (jj >> 1); x = (jj & 1) * 57; }
  size_t addr = ((size_t)(b*NHP + y)*NHP + x)*256 + q*8;
  uint4 z = make_uint4(0u,0u,0u,0u);
  *(uint4*)(xbp + addr) = z;
  *(uint4*)(t1b + addr) = z;
}

// ---------------------------------------------------------------------------
// P1: x NCHW fp32 -> xbp padded NHWC bf16 (interior only)
// ---------------------------------------------------------------------------
__global__ __launch_bounds__(256) void prep_x(
    const float* __restrict__ x, unsigned short* __restrict__ xbp)
{
  __shared__ float T[64][65];
  const int pxt  = blockIdx.x * 64;       // never crosses b (3136 = 49*64)
  const int cg   = blockIdx.y * 64;
  const int b    = pxt / NHW;
  const int rem0 = pxt % NHW;
  const int t    = threadIdx.x;
  const int pl   = t & 63;
  const int c0   = t >> 6;
  const float* src = x + (size_t)b*NCHW + rem0;
  #pragma unroll
  for (int it = 0; it < 16; ++it) {
    int c = c0 + it*4;
    T[c][pl] = src[(size_t)(cg + c)*NHW + pl];
  }
  __syncthreads();
  const int pr = t >> 5;
  const int cp = t & 31;
  #pragma unroll
  for (int it = 0; it < 8; ++it) {
    int pxl = pr + it*8;
    int rem = rem0 + pxl;
    int ho = rem / NW, wo = rem % NW;
    unsigned int pk = ((unsigned int)f2b(T[cp*2+1][pxl]) << 16) | (unsigned int)f2b(T[cp*2][pxl]);
    *(unsigned int*)(xbp + ((size_t)(b*NHP + ho + 1)*NHP + (wo + 1))*256 + cg + cp*2) = pk;
  }
}

// ---------------------------------------------------------------------------
// P2: w [co][ci][3][3] fp32 -> wp [co][k*256+ci] bf16
// ---------------------------------------------------------------------------
__global__ __launch_bounds__(256) void prep_w(
    const float* __restrict__ w, unsigned short* __restrict__ wp)
{
  int i = blockIdx.x*256 + threadIdx.x;    // 589824 exact
  int co = i / 2304;
  int r  = i % 2304;
  int k  = r >> 8;
  int ci = r & 255;
  wp[i] = f2b(w[((size_t)co*256 + ci)*9 + k]);
}

// P3: off_w [18][256][3][3] -> w3p [32 rows][k*256+ci] bf16, rows 18..31 = 0
__global__ __launch_bounds__(256) void prep_w3(
    const float* __restrict__ ow, unsigned short* __restrict__ w3p)
{
  int i = blockIdx.x*256 + threadIdx.x;    // 73728 exact
  int co = i / 2304;
  int r  = i % 2304;
  int k  = r >> 8;
  int ci = r & 255;
  w3p[i] = (co < 18) ? f2b(ow[((size_t)co*256 + ci)*9 + k]) : (unsigned short)0;
}

// ---------------------------------------------------------------------------
// GEMM1: conv3x3 + BN + ReLU -> t1b padded NHWC bf16
// N-split: BM=64 BN=128 BK=64, 256 thr = 4 waves (2M x 2N), wave tile 32x64
// grid (392,2); XCD swizzle: batch-per-XCD. Prefetch in NAMED scalars (no spill)
// ---------------------------------------------------------------------------
__global__ __launch_bounds__(256, 4) void gemm_conv1(
    const unsigned short* __restrict__ xbp, const unsigned short* __restrict__ w1p,
    const float* __restrict__ gam, const float* __restrict__ bet,
    const float* __restrict__ mu,  const float* __restrict__ var,
    unsigned short* __restrict__ t1b)
{
  __shared__ unsigned short SMEM[12288];     // Al 4096 | Bl 8192 (24KB)
  unsigned short* Al = SMEM;
  unsigned short* Bl = SMEM + 4096;

  const int bx   = blockIdx.x;
  const int nbx  = (bx & 7)*49 + (bx >> 3);   // 392 = 8*49, batch-per-XCD
  const int m0   = nbx * 64;
  const int n0   = blockIdx.y * 128;

  const int t    = threadIdx.x;
  const int lane = t & 63;
  const int wv   = t >> 6;       // 0..3
  const int wvM  = wv & 1;
  const int wvN  = wv >> 1;      // 0..1
  const int quad = lane >> 4;
  const int l15  = lane & 15;

  const int srow = t >> 3;       // 0..31
  const int seg  = t & 7;
  const int sxor = srow & 7;     // (srow+32)&7 == srow&7

  // two A rows per thread: srow and srow+32
  unsigned int pbA0, pbA1;
  {
    int px0 = m0 + srow;
    int b0 = px0 / NHW, rem0 = px0 % NHW;
    pbA0 = ((unsigned int)(b0*NHP + rem0/NW)*NHP + rem0%NW)*256u + seg*8u;
    int px1 = px0 + 32;
    int b1 = px1 / NHW, rem1 = px1 % NHW;
    pbA1 = ((unsigned int)(b1*NHP + rem1/NW)*NHP + rem1%NW)*256u + seg*8u;
  }

  f32x4 acc[2][4];
  #pragma unroll
  for (int i = 0; i < 2; ++i)
    #pragma unroll
    for (int j = 0; j < 4; ++j) acc[i][j] = (f32x4)(0.f);

  uint4 pA0, pA1, pB0, pB1, pB2, pB3;
  {   // prefetch r=0 (k=0 -> ky=kx=0, cic=0)
    pA0 = *(const uint4*)(xbp + pbA0);
    pA1 = *(const uint4*)(xbp + pbA1);
    const unsigned int rb = seg*8u;
    pB0 = *(const uint4*)(w1p + (size_t)(n0 + srow     )*2304 + rb);
    pB1 = *(const uint4*)(w1p + (size_t)(n0 + srow + 32)*2304 + rb);
    pB2 = *(const uint4*)(w1p + (size_t)(n0 + srow + 64)*2304 + rb);
    pB3 = *(const uint4*)(w1p + (size_t)(n0 + srow + 96)*2304 + rb);
  }

  for (int r = 0; r < 36; ++r) {
    __syncthreads();                                      // barrier1 (drains prefetch)
    *(uint4*)(&Al[(srow     )*64 + ((seg ^ sxor)*8)]) = pA0;
    *(uint4*)(&Al[(srow + 32)*64 + ((seg ^ sxor)*8)]) = pA1;
    *(uint4*)(&Bl[(srow     )*64 + ((seg ^ sxor)*8)]) = pB0;
    *(uint4*)(&Bl[(srow + 32)*64 + ((seg ^ sxor)*8)]) = pB1;
    *(uint4*)(&Bl[(srow + 64)*64 + ((seg ^ sxor)*8)]) = pB2;
    *(uint4*)(&Bl[(srow + 96)*64 + ((seg ^ sxor)*8)]) = pB3;
    {   // prefetch r+1 (clamped; redundant reload on last iter)
      const int rn = (r < 35) ? r + 1 : 35;
      const int kn = rn >> 2, cicn = rn & 3;
      const int kyn = kn/3, kxn = kn - kyn*3;
      const unsigned int koff = (unsigned int)((kyn*NHP + kxn)*256 + cicn*64);
      pA0 = *(const uint4*)(xbp + pbA0 + koff);
      pA1 = *(const uint4*)(xbp + pbA1 + koff);
      const unsigned int rb = (unsigned int)(rn*64) + seg*8u;
      pB0 = *(const uint4*)(w1p + (size_t)(n0 + srow     )*2304 + rb);
      pB1 = *(const uint4*)(w1p + (size_t)(n0 + srow + 32)*2304 + rb);
      pB2 = *(const uint4*)(w1p + (size_t)(n0 + srow + 64)*2304 + rb);
      pB3 = *(const uint4*)(w1p + (size_t)(n0 + srow + 96)*2304 + rb);
    }
    soft_barrier();                                       // barrier2: no vmcnt drain
    #pragma unroll
    for (int kk = 0; kk < 2; ++kk) {
      const int s8 = (kk*4 + quad) ^ (l15 & 7);
      bf16x8 af[2], bfr[4];
      #pragma unroll
      for (int mt = 0; mt < 2; ++mt)
        af[mt] = *(const bf16x8*)(&Al[(wvM*32 + mt*16 + l15)*64 + s8*8]);
      #pragma unroll
      for (int nt = 0; nt < 4; ++nt)
        bfr[nt] = *(const bf16x8*)(&Bl[(wvN*64 + nt*16 + l15)*64 + s8*8]);
      #pragma unroll
      for (int mt = 0; mt < 2; ++mt)
        #pragma unroll
        for (int nt = 0; nt < 4; ++nt)
          acc[mt][nt] = __builtin_amdgcn_mfma_f32_16x16x32_bf16(af[mt], bfr[nt], acc[mt][nt], 0, 0, 0);
    }
  }

  // epilogue: BN+ReLU -> per-wave bounce (32px x 72 shorts) -> padded t1b
  __syncthreads();
  unsigned short* Sw = SMEM + wv*2304;     // 4*2304 = 9216 <= 12288
  #pragma unroll
  for (int nt = 0; nt < 4; ++nt) {
    const int co = n0 + wvN*64 + nt*16 + l15;
    const float inv  = gam[co] * rsqrtf(var[co] + EPSV);
    const float beta = bet[co] - mu[co]*inv;
    #pragma unroll
    for (int mt = 0; mt < 2; ++mt) {
      #pragma unroll
      for (int rr = 0; rr < 4; ++rr) {
        const int pxl = mt*16 + quad*4 + rr;
        float val = acc[mt][nt][rr]*inv + beta;
        val = val > 0.f ? val : 0.f;
        Sw[pxl*72 + nt*16 + l15] = f2b(val);
      }
    }
  }
  #pragma unroll
  for (int i = 0; i < 4; ++i) {
    const int pxl = (lane >> 3) + 8*i;
    const int sc  = lane & 7;
    uint4 q = *(const uint4*)(&Sw[pxl*72 + sc*8]);
    const int pg = m0 + wvM*32 + pxl;
    const int bb = pg / NHW, rm = pg % NHW;
    const int hh = rm / NW, ww = rm % NW;
    *(uint4*)(t1b + ((size_t)(bb*NHP + hh + 1)*NHP + ww + 1)*256 + n0 + wvN*64 + sc*8) = q;
  }
}

// ---------------------------------------------------------------------------
// GEMM-OFF: offset conv, split-K x4 (9 rounds each), atomicAdd into toff
// ---------------------------------------------------------------------------
__global__ __launch_bounds__(256, 8) void gemm_off(
    const unsigned short* __restrict__ t1b, const unsigned short* __restrict__ w3p,
    const float* __restrict__ ob, float* __restrict__ toff)
{
  __shared__ unsigned short Al[4096];   // 64x64
  __shared__ unsigned short Bl[2048];   // 32x64

  const int bx  = blockIdx.x;
  const int nbx = (bx & 7)*49 + (bx >> 3);
  const int m0  = nbx * 64;
  const int kc = blockIdx.y;            // K chunk 0..3
  const int t    = threadIdx.x;
  const int lane = t & 63;
  const int wv   = t >> 6;
  const int quad = lane >> 4;
  const int l15  = lane & 15;

  const int arow = t >> 2;      // 0..63
  const int as4  = t & 3;
  const int axor = arow & 7;
  const int pxa  = m0 + arow;
  const int ba   = pxa / NHW, rema = pxa % NHW;
  const unsigned int pbase = ((unsigned int)(ba*NHP + rema/NW)*NHP + rema%NW)*256u;

  const int brow = t >> 3;      // 0..31
  const int bs   = t & 7;

  f32x4 acc[2];
  #pragma unroll
  for (int nt = 0; nt < 2; ++nt) {
    float init = 0.f;
    if (kc == 0) { int co = nt*16 + l15; init = (co < 18) ? ob[co] : 0.f; }
    acc[nt] = (f32x4)(init);
  }

  uint4 pA0, pA1, pB;
  {   // prefetch first round r = kc*9
    const int r = kc*9, k = r >> 2, cic = r & 3;
    const int ky = k/3, kx = k - ky*3;
    const unsigned int base = pbase + (unsigned int)((ky*NHP + kx)*256 + cic*64);
    pA0 = *(const uint4*)(t1b + base + as4*8);
    pA1 = *(const uint4*)(t1b + base + (as4+4)*8);
    pB  = *(const uint4*)(w3p + (size_t)brow*2304 + r*64 + bs*8);
  }

  for (int rr = 0; rr < 9; ++rr) {
    const int r = kc*9 + rr;
    __syncthreads();
    *(uint4*)(&Al[arow*64 + ((as4     ^ axor)*8)]) = pA0;
    *(uint4*)(&Al[arow*64 + (((as4+4) ^ axor)*8)]) = pA1;
    *(uint4*)(&Bl[brow*64 + ((bs ^ (brow & 7))*8)]) = pB;
    {
      const int rn = (rr < 8) ? r + 1 : r;
      const int kn = rn >> 2, cicn = rn & 3;
      const int kyn = kn/3, kxn = kn - kyn*3;
      const unsigned int base = pbase + (unsigned int)((kyn*NHP + kxn)*256 + cicn*64);
      pA0 = *(const uint4*)(t1b + base + as4*8);
      pA1 = *(const uint4*)(t1b + base + (as4+4)*8);
      pB  = *(const uint4*)(w3p + (size_t)brow*2304 + rn*64 + bs*8);
    }
    soft_barrier();
    #pragma unroll
    for (int kk = 0; kk < 2; ++kk) {
      const int s8 = (kk*4 + quad) ^ (l15 & 7);
      bf16x8 af = *(const bf16x8*)(&Al[(wv*16 + l15)*64 + s8*8]);
      #pragma unroll
      for (int nt = 0; nt < 2; ++nt) {
        bf16x8 bfr = *(const bf16x8*)(&Bl[(nt*16 + l15)*64 + s8*8]);
        acc[nt] = __builtin_amdgcn_mfma_f32_16x16x32_bf16(af, bfr, acc[nt], 0, 0, 0);
      }
    }
  }
  #pragma unroll
  for (int nt = 0; nt < 2; ++nt) {
    const int co = nt*16 + l15;
    if (co < 18) {
      #pragma unroll
      for (int rr2 = 0; rr2 < 4; ++rr2) {
        const int pg = m0 + wv*16 + quad*4 + rr2;
        const int bb = pg / NHW, rm = pg % NHW;
        atomicAdd(&toff[(size_t)bb*(18*NHW) + (size_t)co*NHW + rm], acc[nt][rr2]);
      }
    }
  }
}

// ---------------------------------------------------------------------------
// GEMM2: deform_conv + BN + residual + ReLU -> out NCHW fp32
// M-split: BM=32 BN=256 BK=64, 256 thr = 4 waves (1M x 4N), wave tile 32x64
// grid 784; XCD swizzle: one batch per XCD L2. NAMED prefetch scalars (no spill)
// ---------------------------------------------------------------------------
__global__ __launch_bounds__(256, 2) void gemm_deform(
    const unsigned short* __restrict__ t1b, const unsigned short* __restrict__ w2p,
    const float* __restrict__ toff, const float* __restrict__ xres,
    const float* __restrict__ gam, const float* __restrict__ bet,
    const float* __restrict__ mu,  const float* __restrict__ var,
    float* __restrict__ outp)
{
  __shared__ unsigned short SMEM[18432];     // Al 2048 | Bl 16384 (36KB)
  unsigned short* Al = SMEM;
  unsigned short* Bl = SMEM + 2048;

  const int bid  = blockIdx.x;
  const int nb   = (bid & 7)*98 + (bid >> 3);   // 784 = 8*98, batch-per-XCD
  const int m0   = nb * 32;
  const int t    = threadIdx.x;
  const int lane = t & 63;
  const int wv   = t >> 6;       // 0..3 (N groups of 64)
  const int quad = lane >> 4;
  const int l15  = lane & 15;

  const int srow = t >> 3;     // 0..31
  const int seg  = t & 7;
  const int sxor = srow & 7;   // (srow+32*i)&7 == srow&7
  const int px   = m0 + srow;
  const int b    = px / NHW, rem = px % NHW;
  const int ho   = rem / NW, wo = rem % NW;
  const int obb  = b*(18*NHW) + rem;
  const unsigned int prowb = (unsigned int)(b*NHP);

  f32x4 acc[2][4];
  #pragma unroll
  for (int i = 0; i < 2; ++i)
    #pragma unroll
    for (int j = 0; j < 4; ++j) acc[i][j] = (f32x4)(0.f);

  // bilinear coord state for current k
  unsigned int o00, o01, o10, o11;
  float w00, w01, w10, w11;
#define COORDS(KK) {                                                   \
    const int ky_ = (KK)/3, kx_ = (KK) - ky_*3;                        \
    const float offy = toff[obb + (KK)*NHW];                           \
    const float offx = toff[obb + (9+(KK))*NHW];                       \
    const float yf = (float)(ho - 1 + ky_) + offy;                     \
    const float xf = (float)(wo - 1 + kx_) + offx;                     \
    const float y0f = floorf(yf), x0f = floorf(xf);                    \
    const float ty = yf - y0f,   tx = xf - x0f;                        \
    const int y0p = (int)y0f + 1, x0p = (int)x0f + 1;                  \
    const int cy0 = min(max(y0p,   0), NHP-1);                         \
    const int cy1 = min(max(y0p+1, 0), NHP-1);                         \
    const int cx0 = min(max(x0p,   0), NHP-1);                         \
    const int cx1 = min(max(x0p+1, 0), NHP-1);                         \
    w00 = (1.f-ty)*(1.f-tx);  w01 = (1.f-ty)*tx;                       \
    w10 = ty*(1.f-tx);        w11 = ty*tx;                             \
    o00 = ((prowb + cy0)*NHP + cx0)*256u + seg*8u;                     \
    o01 = ((prowb + cy0)*NHP + cx1)*256u + seg*8u;                     \
    o10 = ((prowb + cy1)*NHP + cx0)*256u + seg*8u;                     \
    o11 = ((prowb + cy1)*NHP + cx1)*256u + seg*8u;                     \
  }

  COORDS(0);
  uint4 pc00, pc01, pc10, pc11;
  uint4 pB0, pB1, pB2, pB3, pB4, pB5, pB6, pB7;
  {   // prefetch r=0 (cic=0)
    pc00 = *(const uint4*)(t1b + o00);
    pc01 = *(const uint4*)(t1b + o01);
    pc10 = *(const uint4*)(t1b + o10);
    pc11 = *(const uint4*)(t1b + o11);
    const unsigned int rb = seg*8u;
    pB0 = *(const uint4*)(w2p + (size_t)(srow      )*2304 + rb);
    pB1 = *(const uint4*)(w2p + (size_t)(srow +  32)*2304 + rb);
    pB2 = *(const uint4*)(w2p + (size_t)(srow +  64)*2304 + rb);
    pB3 = *(const uint4*)(w2p + (size_t)(srow +  96)*2304 + rb);
    pB4 = *(const uint4*)(w2p + (size_t)(srow + 128)*2304 + rb);
    pB5 = *(const uint4*)(w2p + (size_t)(srow + 160)*2304 + rb);
    pB6 = *(const uint4*)(w2p + (size_t)(srow + 192)*2304 + rb);
    pB7 = *(const uint4*)(w2p + (size_t)(srow + 224)*2304 + rb);
  }

  for (int r = 0; r < 36; ++r) {
    __syncthreads();                                   // barrier1
    {   // bilinear + pack from prefetched corners -> Al
      uint4 res;
      {
        float a0 = w00*blo(pc00.x) + w01*blo(pc01.x) + w10*blo(pc10.x) + w11*blo(pc11.x);
        float a1 = w00*bhi(pc00.x) + w01*bhi(pc01.x) + w10*bhi(pc10.x) + w11*bhi(pc11.x);
        res.x = pack_trunc(a0, a1);
      }
      {
        float a0 = w00*blo(pc00.y) + w01*blo(pc01.y) + w10*blo(pc10.y) + w11*blo(pc11.y);
        float a1 = w00*bhi(pc00.y) + w01*bhi(pc01.y) + w10*bhi(pc10.y) + w11*bhi(pc11.y);
        res.y = pack_trunc(a0, a1);
      }
      {
        float a0 = w00*blo(pc00.z) + w01*blo(pc01.z) + w10*blo(pc10.z) + w11*blo(pc11.z);
        float a1 = w00*bhi(pc00.z) + w01*bhi(pc01.z) + w10*bhi(pc10.z) + w11*bhi(pc11.z);
        res.z = pack_trunc(a0, a1);
      }
      {
        float a0 = w00*blo(pc00.w) + w01*blo(pc01.w) + w10*blo(pc10.w) + w11*blo(pc11.w);
        float a1 = w00*bhi(pc00.w) + w01*bhi(pc01.w) + w10*bhi(pc10.w) + w11*bhi(pc11.w);
        res.w = pack_trunc(a0, a1);
      }
      *(uint4*)(&Al[srow*64 + ((seg ^ sxor)*8)]) = res;
    }
    *(uint4*)(&Bl[(srow      )*64 + ((seg ^ sxor)*8)]) = pB0;
    *(uint4*)(&Bl[(srow +  32)*64 + ((seg ^ sxor)*8)]) = pB1;
    *(uint4*)(&Bl[(srow +  64)*64 + ((seg ^ sxor)*8)]) = pB2;
    *(uint4*)(&Bl[(srow +  96)*64 + ((seg ^ sxor)*8)]) = pB3;
    *(uint4*)(&Bl[(srow + 128)*64 + ((seg ^ sxor)*8)]) = pB4;
    *(uint4*)(&Bl[(srow + 160)*64 + ((seg ^ sxor)*8)]) = pB5;
    *(uint4*)(&Bl[(srow + 192)*64 + ((seg ^ sxor)*8)]) = pB6;
    *(uint4*)(&Bl[(srow + 224)*64 + ((seg ^ sxor)*8)]) = pB7;
    {   // coords for next k, then prefetch r+1
      if ((r & 3) == 3 && r < 35) COORDS((r+1) >> 2);
      const int rn = (r < 35) ? r + 1 : 35;
      const unsigned int cio = (unsigned int)((rn & 3)*64);
      pc00 = *(const uint4*)(t1b + o00 + cio);
      pc01 = *(const uint4*)(t1b + o01 + cio);
      pc10 = *(const uint4*)(t1b + o10 + cio);
      pc11 = *(const uint4*)(t1b + o11 + cio);
      const unsigned int rb = (unsigned int)(rn*64) + seg*8u;
      pB0 = *(const uint4*)(w2p + (size_t)(srow      )*2304 + rb);
      pB1 = *(const uint4*)(w2p + (size_t)(srow +  32)*2304 + rb);
      pB2 = *(const uint4*)(w2p + (size_t)(srow +  64)*2304 + rb);
      pB3 = *(const uint4*)(w2p + (size_t)(srow +  96)*2304 + rb);
      pB4 = *(const uint4*)(w2p + (size_t)(srow + 128)*2304 + rb);
      pB5 = *(const uint4*)(w2p + (size_t)(srow + 160)*2304 + rb);
      pB6 = *(const uint4*)(w2p + (size_t)(srow + 192)*2304 + rb);
      pB7 = *(const uint4*)(w2p + (size_t)(srow + 224)*2304 + rb);
    }
    soft_barrier();                                    // barrier2: no vmcnt drain
    #pragma unroll
    for (int kk = 0; kk < 2; ++kk) {
      const int s8 = (kk*4 + quad) ^ (l15 & 7);
      bf16x8 af[2], bfr[4];
      #pragma unroll
      for (int mt = 0; mt < 2; ++mt)
        af[mt] = *(const bf16x8*)(&Al[(mt*16 + l15)*64 + s8*8]);
      #pragma unroll
      for (int nt = 0; nt < 4; ++nt)
        bfr[nt] = *(const bf16x8*)(&Bl[(wv*64 + nt*16 + l15)*64 + s8*8]);
      #pragma unroll
      for (int mt = 0; mt < 2; ++mt)
        #pragma unroll
        for (int nt = 0; nt < 4; ++nt)
          acc[mt][nt] = __builtin_amdgcn_mfma_f32_16x16x32_bf16(af[mt], bfr[nt], acc[mt][nt], 0, 0, 0);
    }
  }
#undef COORDS

  // epilogue: per-wave f32 bounce (32px x 33), 2 co-halves -> coalesced NCHW
  __syncthreads();
  float* Sl = (float*)SMEM + wv*1056;     // 4*4224B = 16.9KB <= 36KB
  const int pxl_r = lane & 31;
  const int csel  = lane >> 5;
  const int pg    = m0 + pxl_r;
  const int bo    = pg / NHW, remo = pg % NHW;
  const size_t obase = (size_t)bo*NCHW + remo;
  #pragma unroll
  for (int h = 0; h < 2; ++h) {
    #pragma unroll
    for (int nt2 = 0; nt2 < 2; ++nt2) {
      const int nt = h*2 + nt2;
      #pragma unroll
      for (int mt = 0; mt < 2; ++mt) {
        #pragma unroll
        for (int rr = 0; rr < 4; ++rr) {
          const int pxl = mt*16 + quad*4 + rr;
          Sl[pxl*33 + nt2*16 + l15] = acc[mt][nt][rr];
        }
      }
    }
    #pragma unroll
    for (int j = 0; j < 16; ++j) {
      const int col = csel*16 + j;
      const int co  = wv*64 + h*32 + col;
      const float inv  = gam[co] * rsqrtf(var[co] + EPSV);
      const float beta = bet[co] - mu[co]*inv;
      const size_t off = obase + (size_t)co*NHW;
      float val = Sl[pxl_r*33 + col];
      float o = val*inv + beta + xres[off];
      outp[off] = o > 0.f ? o : 0.f;
    }
  }
}

extern "C" void kernel_launch(void* const* d_in, const int* in_sizes, int n_in,
                              void* d_out, int out_size, void* d_ws, size_t ws_size,
                              hipStream_t stream) {
  const float* x   = (const float*)d_in[0];
  const float* w1  = (const float*)d_in[1];
  const float* g1  = (const float*)d_in[2];
  const float* b1  = (const float*)d_in[3];
  const float* m1  = (const float*)d_in[4];
  const float* v1  = (const float*)d_in[5];
  const float* ow  = (const float*)d_in[6];
  const float* ob  = (const float*)d_in[7];
  const float* w2  = (const float*)d_in[8];
  const float* g2  = (const float*)d_in[9];
  const float* b2  = (const float*)d_in[10];
  const float* m2  = (const float*)d_in[11];
  const float* v2  = (const float*)d_in[12];
  float* out = (float*)d_out;

  const size_t PADSZ = (size_t)NB*NHP*NHP*256;
  unsigned short* xbp = (unsigned short*)d_ws;
  unsigned short* t1b = xbp + PADSZ;
  float*          tof = (float*)(t1b + PADSZ);
  unsigned short* w1p = (unsigned short*)(tof + (size_t)NB*18*NHW);
  unsigned short* w2p = w1p + (size_t)589824;
  unsigned short* w3p = w2p + (size_t)589824;

  clear_borders<<<228, 256, 0, stream>>>(xbp, t1b);
  dim3 gp(392, 4, 1);
  prep_x<<<gp, 256, 0, stream>>>(x, xbp);
  prep_w<<<2304, 256, 0, stream>>>(w1, w1p);
  prep_w<<<2304, 256, 0, stream>>>(w2, w2p);
  prep_w3<<<288, 256, 0, stream>>>(ow, w3p);
  hipMemsetAsync(tof, 0, (size_t)NB*18*NHW*sizeof(float), stream);

  dim3 g1d(392, 2, 1);
  gemm_conv1<<<g1d, 256, 0, stream>>>(xbp, w1p, g1, b1, m1, v1, t1b);
  dim3 go(392, 4, 1);
  gemm_off<<<go, 256, 0, stream>>>(t1b, w3p, ob, tof);
  gemm_deform<<<784, 256, 0, stream>>>(t1b, w2p, tof, x, g2, b2, m2, v2, out);
}

// Round 4
// 250.658 us; speedup vs baseline: 2.5718x; 1.1106x over previous
//
#include <hip/hip_runtime.h>

#define NB 8
#define NH 56
#define NW 56
#define NHW 3136          // NH*NW
#define NCHW 802816
#define NPIX 25088        // NB*NHW
#define NHP 58            // padded dim
#define EPSV 1e-5f
#define BUFS 20480        // shorts per LDS buffer: Al 4096 | Bl 16384

typedef float f32x4 __attribute__((ext_vector_type(4)));
typedef __bf16 bf16x8 __attribute__((ext_vector_type(8)));

__device__ __forceinline__ unsigned short f2b(float f) {   // RNE (epilogues)
  unsigned int u = __float_as_uint(f);
  u += 0x7FFFu + ((u >> 16) & 1u);
  return (unsigned short)(u >> 16);
}
__device__ __forceinline__ float blo(unsigned int u){ return __uint_as_float(u << 16); }
__device__ __forceinline__ float bhi(unsigned int u){ return __uint_as_float(u & 0xFFFF0000u); }
// pack 2 fp32 -> 2 bf16 (truncation) in ONE v_perm
__device__ __forceinline__ unsigned int pack_trunc(float f0, float f1) {
  return __builtin_amdgcn_perm(__float_as_uint(f1), __float_as_uint(f0), 0x07060302u);
}
// barrier WITHOUT vmcnt drain: ds ops visible (lgkmcnt 0), prefetch loads stay in flight
__device__ __forceinline__ void soft_barrier() {
  __builtin_amdgcn_s_waitcnt(0xC07F);   // vmcnt=63, expcnt=7, lgkmcnt=0
  __builtin_amdgcn_s_barrier();
}

// ---------------------------------------------------------------------------
// P0: zero the 1px borders of xbp and t1b
// ---------------------------------------------------------------------------
__global__ __launch_bounds__(256) void clear_borders(
    unsigned short* __restrict__ xbp, unsigned short* __restrict__ t1b)
{
  int i = blockIdx.x*256 + threadIdx.x;        // 58368 exact
  int q = i & 31; int pid = i >> 5;
  int b = pid / 228, j = pid % 228;
  int y, x;
  if (j < 58)       { y = 0;  x = j; }
  else if (j < 116) { y = 57; x = j - 58; }
  else { int jj = j - 116; y = 1 + (jj >> 1); x = (jj & 1) * 57; }
  size_t addr = ((size_t)(b*NHP + y)*NHP + x)*256 + q*8;
  uint4 z = make_uint4(0u,0u,0u,0u);
  *(uint4*)(xbp + addr) = z;
  *(uint4*)(t1b + addr) = z;
}

// ---------------------------------------------------------------------------
// P1: x NCHW fp32 -> xbp padded NHWC bf16 (interior only)
// ---------------------------------------------------------------------------
__global__ __launch_bounds__(256) void prep_x(
    const float* __restrict__ x, unsigned short* __restrict__ xbp)
{
  __shared__ float T[64][65];
  const int pxt  = blockIdx.x * 64;       // never crosses b (3136 = 49*64)
  const int cg   = blockIdx.y * 64;
  const int b    = pxt / NHW;
  const int rem0 = pxt % NHW;
  const int t    = threadIdx.x;
  const int pl   = t & 63;
  const int c0   = t >> 6;
  const float* src = x + (size_t)b*NCHW + rem0;
  #pragma unroll
  for (int it = 0; it < 16; ++it) {
    int c = c0 + it*4;
    T[c][pl] = src[(size_t)(cg + c)*NHW + pl];
  }
  __syncthreads();
  const int pr = t >> 5;
  const int cp = t & 31;
  #pragma unroll
  for (int it = 0; it < 8; ++it) {
    int pxl = pr + it*8;
    int rem = rem0 + pxl;
    int ho = rem / NW, wo = rem % NW;
    unsigned int pk = ((unsigned int)f2b(T[cp*2+1][pxl]) << 16) | (unsigned int)f2b(T[cp*2][pxl]);
    *(unsigned int*)(xbp + ((size_t)(b*NHP + ho + 1)*NHP + (wo + 1))*256 + cg + cp*2) = pk;
  }
}

// ---------------------------------------------------------------------------
// P2: w [co][ci][3][3] fp32 -> wp [co][k*256+ci] bf16
// ---------------------------------------------------------------------------
__global__ __launch_bounds__(256) void prep_w(
    const float* __restrict__ w, unsigned short* __restrict__ wp)
{
  int i = blockIdx.x*256 + threadIdx.x;    // 589824 exact
  int co = i / 2304;
  int r  = i % 2304;
  int k  = r >> 8;
  int ci = r & 255;
  wp[i] = f2b(w[((size_t)co*256 + ci)*9 + k]);
}

// P3: off_w [18][256][3][3] -> w3p [32 rows][k*256+ci] bf16, rows 18..31 = 0
__global__ __launch_bounds__(256) void prep_w3(
    const float* __restrict__ ow, unsigned short* __restrict__ w3p)
{
  int i = blockIdx.x*256 + threadIdx.x;    // 73728 exact
  int co = i / 2304;
  int r  = i % 2304;
  int k  = r >> 8;
  int ci = r & 255;
  w3p[i] = (co < 18) ? f2b(ow[((size_t)co*256 + ci)*9 + k]) : (unsigned short)0;
}

// ---------------------------------------------------------------------------
// GEMM1: conv3x3 + BN + ReLU -> t1b padded NHWC bf16
// BM=64 BN=256 BK=64, 512 thr = 8 waves (2M x 4N), wave tile 32x64; grid 392
// LDS DOUBLE-BUFFER, ONE soft barrier per round (no vmcnt drain anywhere in loop)
// XCD swizzle: 49 consecutive blocks (= one batch) per XCD
// ---------------------------------------------------------------------------
__global__ __launch_bounds__(512, 4) void gemm_conv1(
    const unsigned short* __restrict__ xbp, const unsigned short* __restrict__ w1p,
    const float* __restrict__ gam, const float* __restrict__ bet,
    const float* __restrict__ mu,  const float* __restrict__ var,
    unsigned short* __restrict__ t1b)
{
  __shared__ unsigned short SMEM[2*BUFS];    // 80KB: two of (Al 4096 | Bl 16384)

  const int bx   = blockIdx.x;
  const int nbx  = (bx & 7)*49 + (bx >> 3);   // 392 = 8*49, batch-per-XCD
  const int m0   = nbx * 64;
  const int t    = threadIdx.x;
  const int lane = t & 63;
  const int wv   = t >> 6;
  const int wvM  = wv & 1;
  const int wvN  = wv >> 1;
  const int quad = lane >> 4;
  const int l15  = lane & 15;

  const int srow = t >> 3;     // 0..63
  const int seg  = t & 7;
  const int sxor = srow & 7;
  const int px  = m0 + srow;
  const int b   = px / NHW, rem = px % NHW;
  const int ho  = rem / NW, wo = rem % NW;
  const unsigned int pbase = ((unsigned int)(b*NHP + ho)*NHP + wo)*256u + seg*8u;

  f32x4 acc[2][4];
  #pragma unroll
  for (int i = 0; i < 2; ++i)
    #pragma unroll
    for (int j = 0; j < 4; ++j) acc[i][j] = (f32x4)(0.f);

  uint4 pA, pB0, pB1, pB2, pB3;
  {   // prologue: r=0 -> buf0, prefetch r=1 into regs
    pA  = *(const uint4*)(xbp + pbase);
    const unsigned int rb = seg*8u;
    pB0 = *(const uint4*)(w1p + (size_t)(srow      )*2304 + rb);
    pB1 = *(const uint4*)(w1p + (size_t)(srow +  64)*2304 + rb);
    pB2 = *(const uint4*)(w1p + (size_t)(srow + 128)*2304 + rb);
    pB3 = *(const uint4*)(w1p + (size_t)(srow + 192)*2304 + rb);
    *(uint4*)(&SMEM[srow*64 + ((seg ^ sxor)*8)]) = pA;
    *(uint4*)(&SMEM[4096 + (srow      )*64 + ((seg ^ sxor)*8)]) = pB0;
    *(uint4*)(&SMEM[4096 + (srow +  64)*64 + ((seg ^ sxor)*8)]) = pB1;
    *(uint4*)(&SMEM[4096 + (srow + 128)*64 + ((seg ^ sxor)*8)]) = pB2;
    *(uint4*)(&SMEM[4096 + (srow + 192)*64 + ((seg ^ sxor)*8)]) = pB3;
    // r=1: k=0, cic=1 -> koff=64
    pA  = *(const uint4*)(xbp + pbase + 64u);
    const unsigned int rb1 = 64u + seg*8u;
    pB0 = *(const uint4*)(w1p + (size_t)(srow      )*2304 + rb1);
    pB1 = *(const uint4*)(w1p + (size_t)(srow +  64)*2304 + rb1);
    pB2 = *(const uint4*)(w1p + (size_t)(srow + 128)*2304 + rb1);
    pB3 = *(const uint4*)(w1p + (size_t)(srow + 192)*2304 + rb1);
    soft_barrier();
  }

  for (int r = 0; r < 36; ++r) {
    unsigned short* Ac = SMEM + (r & 1)*BUFS;
    unsigned short* Bc = Ac + 4096;
    unsigned short* An = SMEM + ((r + 1) & 1)*BUFS;
    unsigned short* Bn = An + 4096;
    // write prefetched r+1 into next buffer (vmcnt waits are per-data, no barrier)
    *(uint4*)(&An[srow*64 + ((seg ^ sxor)*8)]) = pA;
    *(uint4*)(&Bn[(srow      )*64 + ((seg ^ sxor)*8)]) = pB0;
    *(uint4*)(&Bn[(srow +  64)*64 + ((seg ^ sxor)*8)]) = pB1;
    *(uint4*)(&Bn[(srow + 128)*64 + ((seg ^ sxor)*8)]) = pB2;
    *(uint4*)(&Bn[(srow + 192)*64 + ((seg ^ sxor)*8)]) = pB3;
    {   // prefetch r+2 (clamped; redundant reload at the tail)
      const int rn = (r < 34) ? r + 2 : 35;
      const int kn = rn >> 2, cicn = rn & 3;
      const int kyn = kn/3, kxn = kn - kyn*3;
      pA  = *(const uint4*)(xbp + pbase + (unsigned int)((kyn*NHP + kxn)*256 + cicn*64));
      const unsigned int rb = (unsigned int)(rn*64) + seg*8u;
      pB0 = *(const uint4*)(w1p + (size_t)(srow      )*2304 + rb);
      pB1 = *(const uint4*)(w1p + (size_t)(srow +  64)*2304 + rb);
      pB2 = *(const uint4*)(w1p + (size_t)(srow + 128)*2304 + rb);
      pB3 = *(const uint4*)(w1p + (size_t)(srow + 192)*2304 + rb);
    }
    // MFMA from current buffer (data completed before previous barrier)
    #pragma unroll
    for (int kk = 0; kk < 2; ++kk) {
      const int s8 = (kk*4 + quad) ^ (l15 & 7);
      bf16x8 af[2], bfr[4];
      #pragma unroll
      for (int mt = 0; mt < 2; ++mt)
        af[mt] = *(const bf16x8*)(&Ac[(wvM*32 + mt*16 + l15)*64 + s8*8]);
      #pragma unroll
      for (int nt = 0; nt < 4; ++nt)
        bfr[nt] = *(const bf16x8*)(&Bc[(wvN*64 + nt*16 + l15)*64 + s8*8]);
      #pragma unroll
      for (int mt = 0; mt < 2; ++mt)
        #pragma unroll
        for (int nt = 0; nt < 4; ++nt)
          acc[mt][nt] = __builtin_amdgcn_mfma_f32_16x16x32_bf16(af[mt], bfr[nt], acc[mt][nt], 0, 0, 0);
    }
    soft_barrier();   // single barrier per round: ds ops drained, loads keep flying
  }

  // epilogue: BN+ReLU -> per-wave bounce (32px x 72 shorts) -> padded t1b
  __syncthreads();
  unsigned short* Sw = SMEM + wv*2304;
  #pragma unroll
  for (int nt = 0; nt < 4; ++nt) {
    const int co = wvN*64 + nt*16 + l15;
    const float inv  = gam[co] * rsqrtf(var[co] + EPSV);
    const float beta = bet[co] - mu[co]*inv;
    #pragma unroll
    for (int mt = 0; mt < 2; ++mt) {
      #pragma unroll
      for (int rr = 0; rr < 4; ++rr) {
        const int pxl = mt*16 + quad*4 + rr;
        float val = acc[mt][nt][rr]*inv + beta;
        val = val > 0.f ? val : 0.f;
        Sw[pxl*72 + nt*16 + l15] = f2b(val);
      }
    }
  }
  #pragma unroll
  for (int i = 0; i < 4; ++i) {
    const int pxl = (lane >> 3) + 8*i;
    const int sc  = lane & 7;
    uint4 q = *(const uint4*)(&Sw[pxl*72 + sc*8]);
    const int pg = m0 + wvM*32 + pxl;
    const int bb = pg / NHW, rm = pg % NHW;
    const int hh = rm / NW, ww = rm % NW;
    *(uint4*)(t1b + ((size_t)(bb*NHP + hh + 1)*NHP + ww + 1)*256 + wvN*64 + sc*8) = q;
  }
}

// ---------------------------------------------------------------------------
// GEMM-OFF: offset conv, split-K x4 (9 rounds each), atomicAdd into toff
// ---------------------------------------------------------------------------
__global__ __launch_bounds__(256, 8) void gemm_off(
    const unsigned short* __restrict__ t1b, const unsigned short* __restrict__ w3p,
    const float* __restrict__ ob, float* __restrict__ toff)
{
  __shared__ unsigned short Al[4096];   // 64x64
  __shared__ unsigned short Bl[2048];   // 32x64

  const int bx  = blockIdx.x;
  const int nbx = (bx & 7)*49 + (bx >> 3);
  const int m0  = nbx * 64;
  const int kc = blockIdx.y;            // K chunk 0..3
  const int t    = threadIdx.x;
  const int lane = t & 63;
  const int wv   = t >> 6;
  const int quad = lane >> 4;
  const int l15  = lane & 15;

  const int arow = t >> 2;      // 0..63
  const int as4  = t & 3;
  const int axor = arow & 7;
  const int pxa  = m0 + arow;
  const int ba   = pxa / NHW, rema = pxa % NHW;
  const unsigned int pbase = ((unsigned int)(ba*NHP + rema/NW)*NHP + rema%NW)*256u;

  const int brow = t >> 3;      // 0..31
  const int bs   = t & 7;

  f32x4 acc[2];
  #pragma unroll
  for (int nt = 0; nt < 2; ++nt) {
    float init = 0.f;
    if (kc == 0) { int co = nt*16 + l15; init = (co < 18) ? ob[co] : 0.f; }
    acc[nt] = (f32x4)(init);
  }

  uint4 pA0, pA1, pB;
  {   // prefetch first round r = kc*9
    const int r = kc*9, k = r >> 2, cic = r & 3;
    const int ky = k/3, kx = k - ky*3;
    const unsigned int base = pbase + (unsigned int)((ky*NHP + kx)*256 + cic*64);
    pA0 = *(const uint4*)(t1b + base + as4*8);
    pA1 = *(const uint4*)(t1b + base + (as4+4)*8);
    pB  = *(const uint4*)(w3p + (size_t)brow*2304 + r*64 + bs*8);
  }

  for (int rr = 0; rr < 9; ++rr) {
    const int r = kc*9 + rr;
    __syncthreads();
    *(uint4*)(&Al[arow*64 + ((as4     ^ axor)*8)]) = pA0;
    *(uint4*)(&Al[arow*64 + (((as4+4) ^ axor)*8)]) = pA1;
    *(uint4*)(&Bl[brow*64 + ((bs ^ (brow & 7))*8)]) = pB;
    {
      const int rn = (rr < 8) ? r + 1 : r;
      const int kn = rn >> 2, cicn = rn & 3;
      const int kyn = kn/3, kxn = kn - kyn*3;
      const unsigned int base = pbase + (unsigned int)((kyn*NHP + kxn)*256 + cicn*64);
      pA0 = *(const uint4*)(t1b + base + as4*8);
      pA1 = *(const uint4*)(t1b + base + (as4+4)*8);
      pB  = *(const uint4*)(w3p + (size_t)brow*2304 + rn*64 + bs*8);
    }
    soft_barrier();
    #pragma unroll
    for (int kk = 0; kk < 2; ++kk) {
      const int s8 = (kk*4 + quad) ^ (l15 & 7);
      bf16x8 af = *(const bf16x8*)(&Al[(wv*16 + l15)*64 + s8*8]);
      #pragma unroll
      for (int nt = 0; nt < 2; ++nt) {
        bf16x8 bfr = *(const bf16x8*)(&Bl[(nt*16 + l15)*64 + s8*8]);
        acc[nt] = __builtin_amdgcn_mfma_f32_16x16x32_bf16(af, bfr, acc[nt], 0, 0, 0);
      }
    }
  }
  #pragma unroll
  for (int nt = 0; nt < 2; ++nt) {
    const int co = nt*16 + l15;
    if (co < 18) {
      #pragma unroll
      for (int rr2 = 0; rr2 < 4; ++rr2) {
        const int pg = m0 + wv*16 + quad*4 + rr2;
        const int bb = pg / NHW, rm = pg % NHW;
        atomicAdd(&toff[(size_t)bb*(18*NHW) + (size_t)co*NHW + rm], acc[nt][rr2]);
      }
    }
  }
}

// ---------------------------------------------------------------------------
// GEMM2: deform_conv + BN + residual + ReLU -> out NCHW fp32
// BM=64 BN=256 BK=64, 512 thr = 8 waves; LDS double-buffer, 1 barrier/round
// XCD swizzle: one batch per XCD L2
// ---------------------------------------------------------------------------
__global__ __launch_bounds__(512, 4) void gemm_deform(
    const unsigned short* __restrict__ t1b, const unsigned short* __restrict__ w2p,
    const float* __restrict__ toff, const float* __restrict__ xres,
    const float* __restrict__ gam, const float* __restrict__ bet,
    const float* __restrict__ mu,  const float* __restrict__ var,
    float* __restrict__ outp)
{
  __shared__ unsigned short SMEM[2*BUFS];    // 80KB

  const int bid  = blockIdx.x;
  const int nb   = (bid & 7)*49 + (bid >> 3);   // 392 = 8*49
  const int m0   = nb * 64;
  const int t    = threadIdx.x;
  const int lane = t & 63;
  const int wv   = t >> 6;
  const int wvM  = wv & 1;
  const int wvN  = wv >> 1;
  const int quad = lane >> 4;
  const int l15  = lane & 15;

  const int srow = t >> 3;     // 0..63
  const int seg  = t & 7;
  const int sxor = srow & 7;
  const int px   = m0 + srow;
  const int b    = px / NHW, rem = px % NHW;
  const int ho   = rem / NW, wo = rem % NW;
  const int obb  = b*(18*NHW) + rem;
  const unsigned int prowb = (unsigned int)(b*NHP);

  f32x4 acc[2][4];
  #pragma unroll
  for (int i = 0; i < 2; ++i)
    #pragma unroll
    for (int j = 0; j < 4; ++j) acc[i][j] = (f32x4)(0.f);

  // bilinear coord state for current k
  unsigned int o00, o01, o10, o11;
  float w00, w01, w10, w11;
#define COORDS(KK) {                                                   \
    const int ky_ = (KK)/3, kx_ = (KK) - ky_*3;                        \
    const float offy = toff[obb + (KK)*NHW];                           \
    const float offx = toff[obb + (9+(KK))*NHW];                       \
    const float yf = (float)(ho - 1 + ky_) + offy;                     \
    const float xf = (float)(wo - 1 + kx_) + offx;                     \
    const float y0f = floorf(yf), x0f = floorf(xf);                    \
    const float ty = yf - y0f,   tx = xf - x0f;                        \
    const int y0p = (int)y0f + 1, x0p = (int)x0f + 1;                  \
    const int cy0 = min(max(y0p,   0), NHP-1);                         \
    const int cy1 = min(max(y0p+1, 0), NHP-1);                         \
    const int cx0 = min(max(x0p,   0), NHP-1);                         \
    const int cx1 = min(max(x0p+1, 0), NHP-1);                         \
    w00 = (1.f-ty)*(1.f-tx);  w01 = (1.f-ty)*tx;                       \
    w10 = ty*(1.f-tx);        w11 = ty*tx;                             \
    o00 = ((prowb + cy0)*NHP + cx0)*256u + seg*8u;                     \
    o01 = ((prowb + cy0)*NHP + cx1)*256u + seg*8u;                     \
    o10 = ((prowb + cy1)*NHP + cx0)*256u + seg*8u;                     \
    o11 = ((prowb + cy1)*NHP + cx1)*256u + seg*8u;                     \
  }

// bilinear + pack the 4 prefetched corners -> one uint4 row -> LDS dest
#define PACK_WRITE(DST) {                                                        \
    uint4 res;                                                                   \
    { float a0 = w00*blo(pc00.x) + w01*blo(pc01.x) + w10*blo(pc10.x) + w11*blo(pc11.x); \
      float a1 = w00*bhi(pc00.x) + w01*bhi(pc01.x) + w10*bhi(pc10.x) + w11*bhi(pc11.x); \
      res.x = pack_trunc(a0, a1); }                                              \
    { float a0 = w00*blo(pc00.y) + w01*blo(pc01.y) + w10*blo(pc10.y) + w11*blo(pc11.y); \
      float a1 = w00*bhi(pc00.y) + w01*bhi(pc01.y) + w10*bhi(pc10.y) + w11*bhi(pc11.y); \
      res.y = pack_trunc(a0, a1); }                                              \
    { float a0 = w00*blo(pc00.z) + w01*blo(pc01.z) + w10*blo(pc10.z) + w11*blo(pc11.z); \
      float a1 = w00*bhi(pc00.z) + w01*bhi(pc01.z) + w10*bhi(pc10.z) + w11*bhi(pc11.z); \
      res.z = pack_trunc(a0, a1); }                                              \
    { float a0 = w00*blo(pc00.w) + w01*blo(pc01.w) + w10*blo(pc10.w) + w11*blo(pc11.w); \
      float a1 = w00*bhi(pc00.w) + w01*bhi(pc01.w) + w10*bhi(pc10.w) + w11*bhi(pc11.w); \
      res.w = pack_trunc(a0, a1); }                                              \
    *(uint4*)(&(DST)[srow*64 + ((seg ^ sxor)*8)]) = res;                         \
  }

  COORDS(0);
  uint4 pc00, pc01, pc10, pc11, pB0, pB1, pB2, pB3;
  {   // prologue: r=0 -> pack into buf0; prefetch r=1 (cio=64) into regs
    pc00 = *(const uint4*)(t1b + o00);
    pc01 = *(const uint4*)(t1b + o01);
    pc10 = *(const uint4*)(t1b + o10);
    pc11 = *(const uint4*)(t1b + o11);
    const unsigned int rb = seg*8u;
    pB0 = *(const uint4*)(w2p + (size_t)(srow      )*2304 + rb);
    pB1 = *(const uint4*)(w2p + (size_t)(srow +  64)*2304 + rb);
    pB2 = *(const uint4*)(w2p + (size_t)(srow + 128)*2304 + rb);
    pB3 = *(const uint4*)(w2p + (size_t)(srow + 192)*2304 + rb);
    PACK_WRITE(SMEM);
    *(uint4*)(&SMEM[4096 + (srow      )*64 + ((seg ^ sxor)*8)]) = pB0;
    *(uint4*)(&SMEM[4096 + (srow +  64)*64 + ((seg ^ sxor)*8)]) = pB1;
    *(uint4*)(&SMEM[4096 + (srow + 128)*64 + ((seg ^ sxor)*8)]) = pB2;
    *(uint4*)(&SMEM[4096 + (srow + 192)*64 + ((seg ^ sxor)*8)]) = pB3;
    // r=1 (cio = 64)
    pc00 = *(const uint4*)(t1b + o00 + 64u);
    pc01 = *(const uint4*)(t1b + o01 + 64u);
    pc10 = *(const uint4*)(t1b + o10 + 64u);
    pc11 = *(const uint4*)(t1b + o11 + 64u);
    const unsigned int rb1 = 64u + seg*8u;
    pB0 = *(const uint4*)(w2p + (size_t)(srow      )*2304 + rb1);
    pB1 = *(const uint4*)(w2p + (size_t)(srow +  64)*2304 + rb1);
    pB2 = *(const uint4*)(w2p + (size_t)(srow + 128)*2304 + rb1);
    pB3 = *(const uint4*)(w2p + (size_t)(srow + 192)*2304 + rb1);
    soft_barrier();
  }

  for (int r = 0; r < 36; ++r) {
    unsigned short* Ac = SMEM + (r & 1)*BUFS;
    unsigned short* Bc = Ac + 4096;
    unsigned short* An = SMEM + ((r + 1) & 1)*BUFS;
    unsigned short* Bn = An + 4096;
    // pack prefetched round r+1 corners (weights of k=(r+1)>>2 still live) -> next buf
    PACK_WRITE(An);
    *(uint4*)(&Bn[(srow      )*64 + ((seg ^ sxor)*8)]) = pB0;
    *(uint4*)(&Bn[(srow +  64)*64 + ((seg ^ sxor)*8)]) = pB1;
    *(uint4*)(&Bn[(srow + 128)*64 + ((seg ^ sxor)*8)]) = pB2;
    *(uint4*)(&Bn[(srow + 192)*64 + ((seg ^ sxor)*8)]) = pB3;
    // coords for the k of round r+2 (only at k boundaries, AFTER pack used old w's)
    if ((r & 3) == 2 && r < 34) COORDS((r + 2) >> 2);
    {   // prefetch r+2 (clamped; redundant reload at the tail)
      const int rn = (r < 34) ? r + 2 : 35;
      const unsigned int cio = (unsigned int)((rn & 3)*64);
      pc00 = *(const uint4*)(t1b + o00 + cio);
      pc01 = *(const uint4*)(t1b + o01 + cio);
      pc10 = *(const uint4*)(t1b + o10 + cio);
      pc11 = *(const uint4*)(t1b + o11 + cio);
      const unsigned int rb = (unsigned int)(rn*64) + seg*8u;
      pB0 = *(const uint4*)(w2p + (size_t)(srow      )*2304 + rb);
      pB1 = *(const uint4*)(w2p + (size_t)(srow +  64)*2304 + rb);
      pB2 = *(const uint4*)(w2p + (size_t)(srow + 128)*2304 + rb);
      pB3 = *(const uint4*)(w2p + (size_t)(srow + 192)*2304 + rb);
    }
    // MFMA from current buffer
    #pragma unroll
    for (int kk = 0; kk < 2; ++kk) {
      const int s8 = (kk*4 + quad) ^ (l15 & 7);
      bf16x8 af[2], bfr[4];
      #pragma unroll
      for (int mt = 0; mt < 2; ++mt)
        af[mt] = *(const bf16x8*)(&Ac[(wvM*32 + mt*16 + l15)*64 + s8*8]);
      #pragma unroll
      for (int nt = 0; nt < 4; ++nt)
        bfr[nt] = *(const bf16x8*)(&Bc[(wvN*64 + nt*16 + l15)*64 + s8*8]);
      #pragma unroll
      for (int mt = 0; mt < 2; ++mt)
        #pragma unroll
        for (int nt = 0; nt < 4; ++nt)
          acc[mt][nt] = __builtin_amdgcn_mfma_f32_16x16x32_bf16(af[mt], bfr[nt], acc[mt][nt], 0, 0, 0);
    }
    soft_barrier();   // single barrier per round
  }
#undef COORDS
#undef PACK_WRITE

  // epilogue: per-wave f32 bounce (32px x 33), 2 co-halves -> coalesced NCHW
  __syncthreads();
  float* Sl = (float*)SMEM + wv*1056;
  const int pxl_r = lane & 31;
  const int csel  = lane >> 5;
  const int pg    = m0 + wvM*32 + pxl_r;
  const int bo    = pg / NHW, remo = pg % NHW;
  const size_t obase = (size_t)bo*NCHW + remo;
  #pragma unroll
  for (int h = 0; h < 2; ++h) {
    #pragma unroll
    for (int nt2 = 0; nt2 < 2; ++nt2) {
      const int nt = h*2 + nt2;
      #pragma unroll
      for (int mt = 0; mt < 2; ++mt) {
        #pragma unroll
        for (int rr = 0; rr < 4; ++rr) {
          const int pxl = mt*16 + quad*4 + rr;
          Sl[pxl*33 + nt2*16 + l15] = acc[mt][nt][rr];
        }
      }
    }
    #pragma unroll
    for (int j = 0; j < 16; ++j) {
      const int col = csel*16 + j;
      const int co  = wvN*64 + h*32 + col;
      const float inv  = gam[co] * rsqrtf(var[co] + EPSV);
      const float beta = bet[co] - mu[co]*inv;
      const size_t off = obase + (size_t)co*NHW;
      float val = Sl[pxl_r*33 + col];
      float o = val*inv + beta + xres[off];
      outp[off] = o > 0.f ? o : 0.f;
    }
  }
}

extern "C" void kernel_launch(void* const* d_in, const int* in_sizes, int n_in,
                              void* d_out, int out_size, void* d_ws, size_t ws_size,
                              hipStream_t stream) {
  const float* x   = (const float*)d_in[0];
  const float* w1  = (const float*)d_in[1];
  const float* g1  = (const float*)d_in[2];
  const float* b1  = (const float*)d_in[3];
  const float* m1  = (const float*)d_in[4];
  const float* v1  = (const float*)d_in[5];
  const float* ow  = (const float*)d_in[6];
  const float* ob  = (const float*)d_in[7];
  const float* w2  = (const float*)d_in[8];
  const float* g2  = (const float*)d_in[9];
  const float* b2  = (const float*)d_in[10];
  const float* m2  = (const float*)d_in[11];
  const float* v2  = (const float*)d_in[12];
  float* out = (float*)d_out;

  const size_t PADSZ = (size_t)NB*NHP*NHP*256;
  unsigned short* xbp = (unsigned short*)d_ws;
  unsigned short* t1b = xbp + PADSZ;
  float*          tof = (float*)(t1b + PADSZ);
  unsigned short* w1p = (unsigned short*)(tof + (size_t)NB*18*NHW);
  unsigned short* w2p = w1p + (size_t)589824;
  unsigned short* w3p = w2p + (size_t)589824;

  clear_borders<<<228, 256, 0, stream>>>(xbp, t1b);
  dim3 gp(392, 4, 1);
  prep_x<<<gp, 256, 0, stream>>>(x, xbp);
  prep_w<<<2304, 256, 0, stream>>>(w1, w1p);
  prep_w<<<2304, 256, 0, stream>>>(w2, w2p);
  prep_w3<<<288, 256, 0, stream>>>(ow, w3p);
  hipMemsetAsync(tof, 0, (size_t)NB*18*NHW*sizeof(float), stream);

  gemm_conv1<<<392, 512, 0, stream>>>(xbp, w1p, g1, b1, m1, v1, t1b);
  dim3 go(392, 4, 1);
  gemm_off<<<go, 256, 0, stream>>>(t1b, w3p, ob, tof);
  gemm_deform<<<392, 512, 0, stream>>>(t1b, w2p, tof, x, g2, b2, m2, v2, out);
}